// Round 9
// baseline (312.860 us; speedup 1.0000x reference)
//
#include <hip/hip_runtime.h>
#include <hip/hip_bf16.h>

// SelectiveDense: out[b,g,u] = relu(sum_k x[b, idx[g,k]] * kern[g,k,u] + bias[u])
// B=8192 D=4096 G=256 K=32 U=64. f32 in/out, bf16 MFMA compute.
// R8: write-stream reduction. 8-row blocks (x1024). Per 32-g window: MFMA ->
//     LDS out-buffer (64KB) -> cooperative row-sequential store phase (all 8
//     waves stream one row's 8KB chunk at a time). Chip-wide concurrent write
//     streams drop 4096 -> ~256 (fill-kernel regime). idx prefetched one
//     window ahead; kb frags reloaded BEFORE stores so no waitcnt ever drains
//     the store queue. Barriers: raw s_barrier + lgkmcnt(0) only.

#define B_ 8192
#define D_ 4096
#define G_ 256
#define K_ 32
#define U_ 64
#define ROWS 8
#define WIN 32          // g's per window
#define GPW 4           // g's per wave per window (WIN / 8 waves)
#define OBS 2048        // out-buffer row stride in f32 (= WIN * U_)
#define XS 4100         // x-tile LDS row stride (ushorts)

typedef short v8s __attribute__((ext_vector_type(8)));     // 8 bf16 MFMA A/B frag
typedef float f32x4 __attribute__((ext_vector_type(4)));   // MFMA C/D frag

__device__ __forceinline__ unsigned short f2bf(float f) {
    unsigned int u = __float_as_uint(f);
    u = (u + 0x7FFFu + ((u >> 16) & 1u)) >> 16;   // round-to-nearest-even
    return (unsigned short)u;
}

// Pre-pass: kernels f32 [G][K][U] -> bf16 frag layout [G][4 tiles][64 lanes][8]
// MFMA B operand for tile t: lane l holds B[k=(l>>4)*8+j][col=l&15], col -> u=4*col+t.
__global__ void prep_kb(const float* __restrict__ kern, unsigned short* __restrict__ kb) {
    int tid = blockIdx.x * blockDim.x + threadIdx.x;   // over G*K*U
    if (tid >= G_ * K_ * U_) return;
    int u = tid & (U_ - 1);
    int k = (tid >> 6) & (K_ - 1);
    int g = tid >> 11;
    int t = u & 3;                        // u-within-quad -> tile index
    int col = u >> 2;                     // quad index -> MFMA column
    int lane = ((k >> 3) << 4) | col;
    int j = k & 7;
    kb[((((g << 2) + t) << 6 | lane) << 3) | j] = f2bf(kern[tid]);
}

__global__ void __launch_bounds__(512) sdense(
        const float* __restrict__ x, const unsigned short* __restrict__ kb,
        const float* __restrict__ bias, const int* __restrict__ idx,
        float* __restrict__ out) {
    extern __shared__ unsigned short lx[];              // [ROWS][XS] bf16 x rows
    float* ob = (float*)(lx + ROWS * XS);               // [ROWS][OBS] f32 out-buf
    const int tid = threadIdx.x;
    const int lane = tid & 63;
    const int w = tid >> 6;               // wave 0..7
    const int b0 = blockIdx.x << 3;       // 8 b-rows per block

    // ---- stage 8 rows of x (f32 -> bf16): wave w -> row w ----
    {
        const float* xr = x + (size_t)(b0 + w) * D_;
        unsigned short* lr = lx + w * XS;
        #pragma unroll
        for (int i = 0; i < 8; ++i) {
            int col = (i << 9) + (lane << 3);      // 8 floats / lane / iter
            float4 v0 = *(const float4*)(xr + col);
            float4 v1 = *(const float4*)(xr + col + 4);
            union { unsigned short u[8]; v8s v; } st;
            st.u[0] = f2bf(v0.x); st.u[1] = f2bf(v0.y);
            st.u[2] = f2bf(v0.z); st.u[3] = f2bf(v0.w);
            st.u[4] = f2bf(v1.x); st.u[5] = f2bf(v1.y);
            st.u[6] = f2bf(v1.z); st.u[7] = f2bf(v1.w);
            *(v8s*)(lr + col) = st.v;              // 16B ds_write
        }
    }
    __syncthreads();

    const int grp = lane >> 4;            // 0..3 (grp>=2 -> duplicate rows, discarded)
    const int l15 = lane & 15;
    const int rowb = (l15 & 7) * XS;      // A-operand row (b), duplicated mod 8
    const int kk0 = grp << 3;
    const float4 bias_v = *(const float4*)(bias + (l15 << 2));  // u = 4*l15 + 0..3
    const v8s* kbv = (const v8s*)kb;

    int4 pia[2][GPW], pib[2][GPW];        // idx, double-banked (1-window lookahead)
    v8s kf[GPW][4];                       // kb frags, single bank (reloaded post-MFMA)

    // prologue: idx + kb for window 0
    #pragma unroll
    for (int j = 0; j < GPW; ++j) {
        const int g = (w << 2) + j;
        const int4* ip = (const int4*)(idx + (g << 5) + kk0);
        pia[0][j] = ip[0]; pib[0][j] = ip[1];
        const v8s* kg = kbv + (g << 8) + lane;
        kf[j][0] = kg[0]; kf[j][1] = kg[64]; kf[j][2] = kg[128]; kf[j][3] = kg[192];
    }

    for (int q = 0; q < 8; ++q) {
        const int cb = q & 1, nb = cb ^ 1;
        const int qn = (q + 1) & 7;       // wraps to 0 on last iter (harmless)

        // prefetch NEXT window's idx (before this window's stores)
        #pragma unroll
        for (int j = 0; j < GPW; ++j) {
            const int g = (qn << 5) + (w << 2) + j;
            const int4* ip = (const int4*)(idx + (g << 5) + kk0);
            pia[nb][j] = ip[0]; pib[nb][j] = ip[1];
        }

        // gather + MFMA for this window's GPW g's
        f32x4 acc[GPW][4];
        #pragma unroll
        for (int j = 0; j < GPW; ++j) {
            union { unsigned short u[8]; v8s v; } A;   // A[m=b dup][k=grp*8+jj]
            A.u[0] = lx[rowb + pia[cb][j].x]; A.u[1] = lx[rowb + pia[cb][j].y];
            A.u[2] = lx[rowb + pia[cb][j].z]; A.u[3] = lx[rowb + pia[cb][j].w];
            A.u[4] = lx[rowb + pib[cb][j].x]; A.u[5] = lx[rowb + pib[cb][j].y];
            A.u[6] = lx[rowb + pib[cb][j].z]; A.u[7] = lx[rowb + pib[cb][j].w];
            f32x4 z = {0.f, 0.f, 0.f, 0.f};
            acc[j][0] = __builtin_amdgcn_mfma_f32_16x16x32_bf16(A.v, kf[j][0], z, 0, 0, 0);
            acc[j][1] = __builtin_amdgcn_mfma_f32_16x16x32_bf16(A.v, kf[j][1], z, 0, 0, 0);
            acc[j][2] = __builtin_amdgcn_mfma_f32_16x16x32_bf16(A.v, kf[j][2], z, 0, 0, 0);
            acc[j][3] = __builtin_amdgcn_mfma_f32_16x16x32_bf16(A.v, kf[j][3], z, 0, 0, 0);
        }

        // reload kb frags for NEXT window now (still before stores -> stores
        // remain the newest vmem ops; nothing ever waits behind them)
        #pragma unroll
        for (int j = 0; j < GPW; ++j) {
            const int g = (qn << 5) + (w << 2) + j;
            const v8s* kg = kbv + (g << 8) + lane;
            kf[j][0] = kg[0]; kf[j][1] = kg[64]; kf[j][2] = kg[128]; kf[j][3] = kg[192];
        }

        // bias + relu + out-buffer write (only grp<2 lanes hold real rows)
        if (grp < 2) {
            #pragma unroll
            for (int j = 0; j < GPW; ++j) {
                const int gl = (w << 2) + j;           // window-local g
                #pragma unroll
                for (int r = 0; r < 4; ++r) {
                    float4 v;
                    v.x = acc[j][0][r] + bias_v.x;
                    v.y = acc[j][1][r] + bias_v.y;
                    v.z = acc[j][2][r] + bias_v.z;
                    v.w = acc[j][3][r] + bias_v.w;
                    v.x = v.x > 0.f ? v.x : 0.f;
                    v.y = v.y > 0.f ? v.y : 0.f;
                    v.z = v.z > 0.f ? v.z : 0.f;
                    v.w = v.w > 0.f ? v.w : 0.f;
                    *(float4*)(ob + ((grp << 2) + r) * OBS + (gl << 6) + (l15 << 2)) = v;
                }
            }
        }
        asm volatile("s_waitcnt lgkmcnt(0)" ::: "memory");
        __builtin_amdgcn_sched_barrier(0);
        __builtin_amdgcn_s_barrier();

        // store phase: rows written sequentially; wave w streams chunk w of
        // each row -> block emits one ~8KB quasi-contiguous burst per row.
        {
            const size_t outoff = (size_t)(q << 11) + (w << 8) + (lane << 2);
            #pragma unroll
            for (int r = 0; r < ROWS; ++r) {
                float4 v = *(const float4*)(ob + r * OBS + (w << 8) + (lane << 2));
                *(float4*)(out + (size_t)(b0 + r) * (G_ * U_) + outoff) = v;
            }
        }
        asm volatile("s_waitcnt lgkmcnt(0)" ::: "memory");
        __builtin_amdgcn_sched_barrier(0);
        __builtin_amdgcn_s_barrier();
    }
}

extern "C" void kernel_launch(void* const* d_in, const int* in_sizes, int n_in,
                              void* d_out, int out_size, void* d_ws, size_t ws_size,
                              hipStream_t stream) {
    const float* x    = (const float*)d_in[0];
    const float* kern = (const float*)d_in[1];
    const float* bias = (const float*)d_in[2];
    const int*   idx  = (const int*)d_in[3];
    float* out = (float*)d_out;
    unsigned short* kb = (unsigned short*)d_ws;   // 1 MiB bf16 kernel frags

    prep_kb<<<(G_ * K_ * U_ + 255) / 256, 256, 0, stream>>>(kern, kb);
    size_t lds = ROWS * XS * sizeof(unsigned short) + ROWS * OBS * sizeof(float);
    sdense<<<B_ / ROWS, 512, lds, stream>>>(x, kb, bias, idx, out);
}

// Round 10
// 172.563 us; speedup vs baseline: 1.8130x; 1.8130x over previous
//
#include <hip/hip_runtime.h>
#include <hip/hip_bf16.h>

// SelectiveDense: out[b,g,u] = relu(sum_k x[b, idx[g,k]] * kern[g,k,u] + bias[u])
// B=8192 D=4096 G=256 K=32 U=64. f32 in/out, bf16 MFMA compute.
// R9 = R5 structure with 8-row blocks, 256 threads, 2 blocks/CU.
//     Theory: within a block all waves drain stores in phase (R7 null); a
//     second independent block per CU overlaps its compute with the first
//     block's store-drain. Direct stores (no R8 LDS round-trip), QG=8
//     (2KB/row/visit), duplicated MFMA rows (grp<2 stores), no q-barrier.

#define B_ 8192
#define D_ 4096
#define G_ 256
#define K_ 32
#define U_ 64
#define ROWS 8
#define QG 8

typedef short v8s __attribute__((ext_vector_type(8)));     // 8 bf16 MFMA A/B frag
typedef float f32x4 __attribute__((ext_vector_type(4)));   // MFMA C/D frag

__device__ __forceinline__ unsigned short f2bf(float f) {
    unsigned int u = __float_as_uint(f);
    u = (u + 0x7FFFu + ((u >> 16) & 1u)) >> 16;   // round-to-nearest-even
    return (unsigned short)u;
}

// Pre-pass: kernels f32 [G][K][U] -> bf16 frag layout [G][4 tiles][64 lanes][8]
// MFMA B operand for tile t: lane l holds B[k=(l>>4)*8+j][col=l&15], col -> u=4*col+t.
__global__ void prep_kb(const float* __restrict__ kern, unsigned short* __restrict__ kb) {
    int tid = blockIdx.x * blockDim.x + threadIdx.x;   // over G*K*U
    if (tid >= G_ * K_ * U_) return;
    int u = tid & (U_ - 1);
    int k = (tid >> 6) & (K_ - 1);
    int g = tid >> 11;
    int t = u & 3;                        // u-within-quad -> tile index
    int col = u >> 2;                     // quad index -> MFMA column
    int lane = ((k >> 3) << 4) | col;
    int j = k & 7;
    kb[((((g << 2) + t) << 6 | lane) << 3) | j] = f2bf(kern[tid]);
}

#define XS 4100   // LDS row stride (ushorts): bank shift 2/row -> gather ~conflict-free

__global__ void __launch_bounds__(256, 2) sdense(
        const float* __restrict__ x, const unsigned short* __restrict__ kb,
        const float* __restrict__ bias, const int* __restrict__ idx,
        float* __restrict__ out) {
    extern __shared__ unsigned short lx[];   // [ROWS][XS] bf16 x rows (65.6KB -> 2 blocks/CU)
    const int tid = threadIdx.x;
    const int b0 = blockIdx.x << 3;       // 8 b-rows per block
    const int lane = tid & 63;
    const int w = tid >> 6;               // wave 0..3

    // ---- stage 8 rows of x (f32 -> bf16): wave w -> rows 2w, 2w+1 ----
    {
        const int row = (w << 1) + (lane >> 5);
        const int l32 = lane & 31;
        const float* xr = x + (size_t)(b0 + row) * D_;
        unsigned short* lr = lx + row * XS;
        #pragma unroll
        for (int i = 0; i < 16; ++i) {
            int col = (i << 8) + (l32 << 3);       // 8 floats / lane / iter
            float4 v0 = *(const float4*)(xr + col);
            float4 v1 = *(const float4*)(xr + col + 4);
            union { unsigned short u[8]; v8s v; } st;
            st.u[0] = f2bf(v0.x); st.u[1] = f2bf(v0.y);
            st.u[2] = f2bf(v0.z); st.u[3] = f2bf(v0.w);
            st.u[4] = f2bf(v1.x); st.u[5] = f2bf(v1.y);
            st.u[6] = f2bf(v1.z); st.u[7] = f2bf(v1.w);
            *(v8s*)(lr + col) = st.v;              // 16B ds_write
        }
    }
    __syncthreads();

    // ---- super-iter: wave w covers g in [32q+8w, 32q+8w+8); free-running ----
    const int grp = lane >> 4;            // 0..3 (grp>=2 -> duplicate rows, discarded)
    const int l15 = lane & 15;
    const int rowb = (l15 & 7) * XS;      // A-operand row (b), duplicated mod 8
    const int kk0 = grp << 3;

    const float4 bias_v = *(const float4*)(bias + (l15 << 2));  // u = 4*l15 + 0..3

    const v8s* kbv = (const v8s*)kb;

    for (int q = 0; q < 8; ++q) {
        const int g0 = (q << 5) + (w << 3);   // 32q + 8w

        f32x4 acc[QG][4];
        #pragma unroll
        for (int j = 0; j < QG; ++j) {
            const int g = g0 + j;
            const int4* ip = (const int4*)(idx + (g << 5) + kk0);
            int4 ia = ip[0], ib = ip[1];
            const v8s* kg = kbv + (g << 8) + lane;
            v8s k0 = kg[0], k1 = kg[64], k2 = kg[128], k3 = kg[192];

            union { unsigned short u[8]; v8s v; } A;  // A[m=b dup][k=grp*8+jj]
            A.u[0] = lx[rowb + ia.x]; A.u[1] = lx[rowb + ia.y];
            A.u[2] = lx[rowb + ia.z]; A.u[3] = lx[rowb + ia.w];
            A.u[4] = lx[rowb + ib.x]; A.u[5] = lx[rowb + ib.y];
            A.u[6] = lx[rowb + ib.z]; A.u[7] = lx[rowb + ib.w];

            f32x4 z = {0.f, 0.f, 0.f, 0.f};
            acc[j][0] = __builtin_amdgcn_mfma_f32_16x16x32_bf16(A.v, k0, z, 0, 0, 0);
            acc[j][1] = __builtin_amdgcn_mfma_f32_16x16x32_bf16(A.v, k1, z, 0, 0, 0);
            acc[j][2] = __builtin_amdgcn_mfma_f32_16x16x32_bf16(A.v, k2, z, 0, 0, 0);
            acc[j][3] = __builtin_amdgcn_mfma_f32_16x16x32_bf16(A.v, k3, z, 0, 0, 0);
        }

        // store phase: only grp<2 lanes hold real rows (0..7).
        // r-outer; per row, 8 sequential dwordx4 = 2KB contiguous per wave-visit.
        if (grp < 2) {
            #pragma unroll
            for (int r = 0; r < 4; ++r) {
                float* obr = out + (size_t)(b0 + (grp << 2) + r) * (G_ * U_)
                                 + (g0 << 6) + (l15 << 2);
                #pragma unroll
                for (int j = 0; j < QG; ++j) {
                    float4 v;
                    v.x = acc[j][0][r] + bias_v.x;
                    v.y = acc[j][1][r] + bias_v.y;
                    v.z = acc[j][2][r] + bias_v.z;
                    v.w = acc[j][3][r] + bias_v.w;
                    v.x = v.x > 0.f ? v.x : 0.f;
                    v.y = v.y > 0.f ? v.y : 0.f;
                    v.z = v.z > 0.f ? v.z : 0.f;
                    v.w = v.w > 0.f ? v.w : 0.f;
                    *(float4*)(obr + (j << 6)) = v;
                }
            }
        }
        // no barrier: block-level overlap comes from the second resident block
    }
}

extern "C" void kernel_launch(void* const* d_in, const int* in_sizes, int n_in,
                              void* d_out, int out_size, void* d_ws, size_t ws_size,
                              hipStream_t stream) {
    const float* x    = (const float*)d_in[0];
    const float* kern = (const float*)d_in[1];
    const float* bias = (const float*)d_in[2];
    const int*   idx  = (const int*)d_in[3];
    float* out = (float*)d_out;
    unsigned short* kb = (unsigned short*)d_ws;   // 1 MiB bf16 kernel frags

    prep_kb<<<(G_ * K_ * U_ + 255) / 256, 256, 0, stream>>>(kern, kb);
    sdense<<<B_ / ROWS, 256, ROWS * XS * sizeof(unsigned short), stream>>>(x, kb, bias, idx, out);
}

// Round 11
// 156.282 us; speedup vs baseline: 2.0019x; 1.1042x over previous
//
#include <hip/hip_runtime.h>
#include <hip/hip_bf16.h>

// SelectiveDense: out[b,g,u] = relu(sum_k x[b, idx[g,k]] * kern[g,k,u] + bias[u])
// B=8192 D=4096 G=256 K=32 U=64. f32 in/out, bf16 MFMA compute.
// R10 = R7 (best, 169.2us) + NON-TEMPORAL x staging loads (single change).
//     x has zero reuse chip-wide; nt loads keep 134MB of stream traffic from
//     evicting the shared 1MiB kb working set out of L2/L3 (R8 measured a
//     ~197MB HBM re-fetch leak: FETCH 331MB vs 134MB ideal).

#define B_ 8192
#define D_ 4096
#define G_ 256
#define K_ 32
#define U_ 64
#define QG 8

typedef short v8s __attribute__((ext_vector_type(8)));     // 8 bf16 MFMA A/B frag
typedef float f32x4 __attribute__((ext_vector_type(4)));   // MFMA C/D frag

__device__ __forceinline__ unsigned short f2bf(float f) {
    unsigned int u = __float_as_uint(f);
    u = (u + 0x7FFFu + ((u >> 16) & 1u)) >> 16;   // round-to-nearest-even
    return (unsigned short)u;
}

// Pre-pass: kernels f32 [G][K][U] -> bf16 frag layout [G][4 tiles][64 lanes][8]
// MFMA B operand for tile t: lane l holds B[k=(l>>4)*8+j][col=l&15], col -> u=4*col+t.
__global__ void prep_kb(const float* __restrict__ kern, unsigned short* __restrict__ kb) {
    int tid = blockIdx.x * blockDim.x + threadIdx.x;   // over G*K*U
    if (tid >= G_ * K_ * U_) return;
    int u = tid & (U_ - 1);
    int k = (tid >> 6) & (K_ - 1);
    int g = tid >> 11;
    int t = u & 3;                        // u-within-quad -> tile index
    int col = u >> 2;                     // quad index -> MFMA column
    int lane = ((k >> 3) << 4) | col;
    int j = k & 7;
    kb[((((g << 2) + t) << 6 | lane) << 3) | j] = f2bf(kern[tid]);
}

#define XS 4100   // LDS row stride (ushorts): bank shift 2/row -> gather ~conflict-free

__global__ void __launch_bounds__(512) sdense(
        const float* __restrict__ x, const unsigned short* __restrict__ kb,
        const float* __restrict__ bias, const int* __restrict__ idx,
        float* __restrict__ out) {
    extern __shared__ unsigned short lx[];   // [16][XS] bf16 x rows
    const int tid = threadIdx.x;
    const int b0 = blockIdx.x << 4;
    const int lane = tid & 63;
    const int w = tid >> 6;               // wave 0..7

    // ---- stage 16 rows of x (f32 -> bf16): wave w -> rows 2w, 2w+1 ----
    // NT loads: x is read exactly once chip-wide; don't pollute L2/L3.
    {
        const int row = (w << 1) + (lane >> 5);
        const int l32 = lane & 31;
        const float* xr = x + (size_t)(b0 + row) * D_;
        unsigned short* lr = lx + row * XS;
        #pragma unroll
        for (int i = 0; i < 16; ++i) {
            int col = (i << 8) + (l32 << 3);       // 8 floats / lane / iter
            f32x4 v0 = __builtin_nontemporal_load((const f32x4*)(xr + col));
            f32x4 v1 = __builtin_nontemporal_load((const f32x4*)(xr + col + 4));
            union { unsigned short u[8]; v8s v; } st;
            st.u[0] = f2bf(v0[0]); st.u[1] = f2bf(v0[1]);
            st.u[2] = f2bf(v0[2]); st.u[3] = f2bf(v0[3]);
            st.u[4] = f2bf(v1[0]); st.u[5] = f2bf(v1[1]);
            st.u[6] = f2bf(v1[2]); st.u[7] = f2bf(v1[3]);
            *(v8s*)(lr + col) = st.v;              // 16B ds_write
        }
    }
    __syncthreads();

    // ---- super-iter: wave w covers g in [64q+8w, 64q+8w+8); free-running ----
    const int grp = lane >> 4;            // 0..3
    const int l15 = lane & 15;
    const int rowb = l15 * XS;            // A-operand: lane gathers x row b=l15
    const int kk0 = grp << 3;

    const float4 bias_v = *(const float4*)(bias + (l15 << 2));  // u = 4*l15 + 0..3

    const v8s* kbv = (const v8s*)kb;

    for (int q = 0; q < 4; ++q) {
        const int g0 = (q << 6) + (w << 3);   // 64q + 8w

        f32x4 acc[QG][4];
        #pragma unroll
        for (int j = 0; j < QG; ++j) {
            const int g = g0 + j;
            const int4* ip = (const int4*)(idx + (g << 5) + kk0);
            int4 ia = ip[0], ib = ip[1];
            const v8s* kg = kbv + (g << 8) + lane;
            v8s k0 = kg[0], k1 = kg[64], k2 = kg[128], k3 = kg[192];

            union { unsigned short u[8]; v8s v; } A;  // A[m=b=l15][k=grp*8+jj]
            A.u[0] = lx[rowb + ia.x]; A.u[1] = lx[rowb + ia.y];
            A.u[2] = lx[rowb + ia.z]; A.u[3] = lx[rowb + ia.w];
            A.u[4] = lx[rowb + ib.x]; A.u[5] = lx[rowb + ib.y];
            A.u[6] = lx[rowb + ib.z]; A.u[7] = lx[rowb + ib.w];

            f32x4 z = {0.f, 0.f, 0.f, 0.f};
            acc[j][0] = __builtin_amdgcn_mfma_f32_16x16x32_bf16(A.v, k0, z, 0, 0, 0);
            acc[j][1] = __builtin_amdgcn_mfma_f32_16x16x32_bf16(A.v, k1, z, 0, 0, 0);
            acc[j][2] = __builtin_amdgcn_mfma_f32_16x16x32_bf16(A.v, k2, z, 0, 0, 0);
            acc[j][3] = __builtin_amdgcn_mfma_f32_16x16x32_bf16(A.v, k3, z, 0, 0, 0);
        }

        // store phase: r-outer; per row, 8 sequential dwordx4 instrs = 2KB contiguous
        #pragma unroll
        for (int r = 0; r < 4; ++r) {
            float* obr = out + (size_t)(b0 + (grp << 2) + r) * (G_ * U_)
                             + (g0 << 6) + (l15 << 2);
            #pragma unroll
            for (int j = 0; j < QG; ++j) {
                float4 v;
                v.x = acc[j][0][r] + bias_v.x;
                v.y = acc[j][1][r] + bias_v.y;
                v.z = acc[j][2][r] + bias_v.z;
                v.w = acc[j][3][r] + bias_v.w;
                v.x = v.x > 0.f ? v.x : 0.f;
                v.y = v.y > 0.f ? v.y : 0.f;
                v.z = v.z > 0.f ? v.z : 0.f;
                v.w = v.w > 0.f ? v.w : 0.f;
                *(float4*)(obr + (j << 6)) = v;
            }
        }
        // no barrier (R7): free-running waves
    }
}

extern "C" void kernel_launch(void* const* d_in, const int* in_sizes, int n_in,
                              void* d_out, int out_size, void* d_ws, size_t ws_size,
                              hipStream_t stream) {
    const float* x    = (const float*)d_in[0];
    const float* kern = (const float*)d_in[1];
    const float* bias = (const float*)d_in[2];
    const int*   idx  = (const int*)d_in[3];
    float* out = (float*)d_out;
    unsigned short* kb = (unsigned short*)d_ws;   // 1 MiB bf16 kernel frags

    prep_kb<<<(G_ * K_ * U_ + 255) / 256, 256, 0, stream>>>(kern, kb);
    sdense<<<B_ / 16, 512, 16 * XS * sizeof(unsigned short), stream>>>(x, kb, bias, idx, out);
}

// Round 12
// 149.877 us; speedup vs baseline: 2.0874x; 1.0427x over previous
//
#include <hip/hip_runtime.h>
#include <hip/hip_bf16.h>

// SelectiveDense: out[b,g,u] = relu(sum_k x[b, idx[g,k]] * kern[g,k,u] + bias[u])
// B=8192 D=4096 G=256 K=32 U=64. f32 in/out, bf16 MFMA compute.
// R11 = R10 (156.3us) + NON-TEMPORAL dwordx4 output stores (single change).
//     R4's nt regression was on SCALAR stores (4B granule, lost L2 write-
//     combining). Now stores are full-line dwordx4 (256B/16-lane group), so
//     bypassing L2 costs nothing and stops 537MB of writes from evicting the
//     shared kb working set; L3 is memory-side and still aggregates writes.

#define B_ 8192
#define D_ 4096
#define G_ 256
#define K_ 32
#define U_ 64
#define QG 8

typedef short v8s __attribute__((ext_vector_type(8)));     // 8 bf16 MFMA A/B frag
typedef float f32x4 __attribute__((ext_vector_type(4)));   // MFMA C/D frag

__device__ __forceinline__ unsigned short f2bf(float f) {
    unsigned int u = __float_as_uint(f);
    u = (u + 0x7FFFu + ((u >> 16) & 1u)) >> 16;   // round-to-nearest-even
    return (unsigned short)u;
}

// Pre-pass: kernels f32 [G][K][U] -> bf16 frag layout [G][4 tiles][64 lanes][8]
// MFMA B operand for tile t: lane l holds B[k=(l>>4)*8+j][col=l&15], col -> u=4*col+t.
__global__ void prep_kb(const float* __restrict__ kern, unsigned short* __restrict__ kb) {
    int tid = blockIdx.x * blockDim.x + threadIdx.x;   // over G*K*U
    if (tid >= G_ * K_ * U_) return;
    int u = tid & (U_ - 1);
    int k = (tid >> 6) & (K_ - 1);
    int g = tid >> 11;
    int t = u & 3;                        // u-within-quad -> tile index
    int col = u >> 2;                     // quad index -> MFMA column
    int lane = ((k >> 3) << 4) | col;
    int j = k & 7;
    kb[((((g << 2) + t) << 6 | lane) << 3) | j] = f2bf(kern[tid]);
}

#define XS 4100   // LDS row stride (ushorts): bank shift 2/row -> gather ~conflict-free

__global__ void __launch_bounds__(512) sdense(
        const float* __restrict__ x, const unsigned short* __restrict__ kb,
        const float* __restrict__ bias, const int* __restrict__ idx,
        float* __restrict__ out) {
    extern __shared__ unsigned short lx[];   // [16][XS] bf16 x rows
    const int tid = threadIdx.x;
    const int b0 = blockIdx.x << 4;
    const int lane = tid & 63;
    const int w = tid >> 6;               // wave 0..7

    // ---- stage 16 rows of x (f32 -> bf16): wave w -> rows 2w, 2w+1 ----
    // NT loads: x is read exactly once chip-wide; don't pollute L2/L3.
    {
        const int row = (w << 1) + (lane >> 5);
        const int l32 = lane & 31;
        const float* xr = x + (size_t)(b0 + row) * D_;
        unsigned short* lr = lx + row * XS;
        #pragma unroll
        for (int i = 0; i < 16; ++i) {
            int col = (i << 8) + (l32 << 3);       // 8 floats / lane / iter
            f32x4 v0 = __builtin_nontemporal_load((const f32x4*)(xr + col));
            f32x4 v1 = __builtin_nontemporal_load((const f32x4*)(xr + col + 4));
            union { unsigned short u[8]; v8s v; } st;
            st.u[0] = f2bf(v0[0]); st.u[1] = f2bf(v0[1]);
            st.u[2] = f2bf(v0[2]); st.u[3] = f2bf(v0[3]);
            st.u[4] = f2bf(v1[0]); st.u[5] = f2bf(v1[1]);
            st.u[6] = f2bf(v1[2]); st.u[7] = f2bf(v1[3]);
            *(v8s*)(lr + col) = st.v;              // 16B ds_write
        }
    }
    __syncthreads();

    // ---- super-iter: wave w covers g in [64q+8w, 64q+8w+8); free-running ----
    const int grp = lane >> 4;            // 0..3
    const int l15 = lane & 15;
    const int rowb = l15 * XS;            // A-operand: lane gathers x row b=l15
    const int kk0 = grp << 3;

    const float4 bias_v = *(const float4*)(bias + (l15 << 2));  // u = 4*l15 + 0..3

    const v8s* kbv = (const v8s*)kb;

    for (int q = 0; q < 4; ++q) {
        const int g0 = (q << 6) + (w << 3);   // 64q + 8w

        f32x4 acc[QG][4];
        #pragma unroll
        for (int j = 0; j < QG; ++j) {
            const int g = g0 + j;
            const int4* ip = (const int4*)(idx + (g << 5) + kk0);
            int4 ia = ip[0], ib = ip[1];
            const v8s* kg = kbv + (g << 8) + lane;
            v8s k0 = kg[0], k1 = kg[64], k2 = kg[128], k3 = kg[192];

            union { unsigned short u[8]; v8s v; } A;  // A[m=b=l15][k=grp*8+jj]
            A.u[0] = lx[rowb + ia.x]; A.u[1] = lx[rowb + ia.y];
            A.u[2] = lx[rowb + ia.z]; A.u[3] = lx[rowb + ia.w];
            A.u[4] = lx[rowb + ib.x]; A.u[5] = lx[rowb + ib.y];
            A.u[6] = lx[rowb + ib.z]; A.u[7] = lx[rowb + ib.w];

            f32x4 z = {0.f, 0.f, 0.f, 0.f};
            acc[j][0] = __builtin_amdgcn_mfma_f32_16x16x32_bf16(A.v, k0, z, 0, 0, 0);
            acc[j][1] = __builtin_amdgcn_mfma_f32_16x16x32_bf16(A.v, k1, z, 0, 0, 0);
            acc[j][2] = __builtin_amdgcn_mfma_f32_16x16x32_bf16(A.v, k2, z, 0, 0, 0);
            acc[j][3] = __builtin_amdgcn_mfma_f32_16x16x32_bf16(A.v, k3, z, 0, 0, 0);
        }

        // store phase: r-outer; per row, 8 sequential NT dwordx4 = 2KB contiguous.
        // nt: full-line writes bypass L2 (no kb eviction), aggregate in
        // memory-side L3 for page-local drain.
        #pragma unroll
        for (int r = 0; r < 4; ++r) {
            float* obr = out + (size_t)(b0 + (grp << 2) + r) * (G_ * U_)
                             + (g0 << 6) + (l15 << 2);
            #pragma unroll
            for (int j = 0; j < QG; ++j) {
                f32x4 v;
                v[0] = acc[j][0][r] + bias_v.x;
                v[1] = acc[j][1][r] + bias_v.y;
                v[2] = acc[j][2][r] + bias_v.z;
                v[3] = acc[j][3][r] + bias_v.w;
                v[0] = v[0] > 0.f ? v[0] : 0.f;
                v[1] = v[1] > 0.f ? v[1] : 0.f;
                v[2] = v[2] > 0.f ? v[2] : 0.f;
                v[3] = v[3] > 0.f ? v[3] : 0.f;
                __builtin_nontemporal_store(v, (f32x4*)(obr + (j << 6)));
            }
        }
        // no barrier (R7): free-running waves
    }
}

extern "C" void kernel_launch(void* const* d_in, const int* in_sizes, int n_in,
                              void* d_out, int out_size, void* d_ws, size_t ws_size,
                              hipStream_t stream) {
    const float* x    = (const float*)d_in[0];
    const float* kern = (const float*)d_in[1];
    const float* bias = (const float*)d_in[2];
    const int*   idx  = (const int*)d_in[3];
    float* out = (float*)d_out;
    unsigned short* kb = (unsigned short*)d_ws;   // 1 MiB bf16 kernel frags

    prep_kb<<<(G_ * K_ * U_ + 255) / 256, 256, 0, stream>>>(kern, kb);
    sdense<<<B_ / 16, 512, 16 * XS * sizeof(unsigned short), stream>>>(x, kb, bias, idx, out);
}

// Round 13
// 148.228 us; speedup vs baseline: 2.1107x; 1.0111x over previous
//
#include <hip/hip_runtime.h>
#include <hip/hip_bf16.h>

// SelectiveDense: out[b,g,u] = relu(sum_k x[b, idx[g,k]] * kern[g,k,u] + bias[u])
// B=8192 D=4096 G=256 K=32 U=64. f32 in/out, bf16 MFMA compute.
// R12 = R11 with ROWS=8 and 1 block/CU (LDS padded to 100KB) — single change:
//     chip-wide concurrent write streams 4096 -> 2048. Clean test of the
//     stream-count theory (R8 was confounded, R9 didn't reduce streams).

#define B_ 8192
#define D_ 4096
#define G_ 256
#define K_ 32
#define U_ 64
#define ROWS 8
#define QG 8

typedef short v8s __attribute__((ext_vector_type(8)));     // 8 bf16 MFMA A/B frag
typedef float f32x4 __attribute__((ext_vector_type(4)));   // MFMA C/D frag

__device__ __forceinline__ unsigned short f2bf(float f) {
    unsigned int u = __float_as_uint(f);
    u = (u + 0x7FFFu + ((u >> 16) & 1u)) >> 16;   // round-to-nearest-even
    return (unsigned short)u;
}

// Pre-pass: kernels f32 [G][K][U] -> bf16 frag layout [G][4 tiles][64 lanes][8]
// MFMA B operand for tile t: lane l holds B[k=(l>>4)*8+j][col=l&15], col -> u=4*col+t.
__global__ void prep_kb(const float* __restrict__ kern, unsigned short* __restrict__ kb) {
    int tid = blockIdx.x * blockDim.x + threadIdx.x;   // over G*K*U
    if (tid >= G_ * K_ * U_) return;
    int u = tid & (U_ - 1);
    int k = (tid >> 6) & (K_ - 1);
    int g = tid >> 11;
    int t = u & 3;                        // u-within-quad -> tile index
    int col = u >> 2;                     // quad index -> MFMA column
    int lane = ((k >> 3) << 4) | col;
    int j = k & 7;
    kb[((((g << 2) + t) << 6 | lane) << 3) | j] = f2bf(kern[tid]);
}

#define XS 4100   // LDS row stride (ushorts): bank shift 2/row -> gather ~conflict-free

__global__ void __launch_bounds__(512) sdense(
        const float* __restrict__ x, const unsigned short* __restrict__ kb,
        const float* __restrict__ bias, const int* __restrict__ idx,
        float* __restrict__ out) {
    extern __shared__ unsigned short lx[];   // [ROWS][XS] bf16 x rows (padded alloc -> 1 block/CU)
    const int tid = threadIdx.x;
    const int b0 = blockIdx.x << 3;       // 8 b-rows per block
    const int lane = tid & 63;
    const int w = tid >> 6;               // wave 0..7

    // ---- stage 8 rows of x (f32 -> bf16): wave w -> row w, NT loads ----
    {
        const float* xr = x + (size_t)(b0 + w) * D_;
        unsigned short* lr = lx + w * XS;
        #pragma unroll
        for (int i = 0; i < 8; ++i) {
            int col = (i << 9) + (lane << 3);      // 8 floats / lane / iter
            f32x4 v0 = __builtin_nontemporal_load((const f32x4*)(xr + col));
            f32x4 v1 = __builtin_nontemporal_load((const f32x4*)(xr + col + 4));
            union { unsigned short u[8]; v8s v; } st;
            st.u[0] = f2bf(v0[0]); st.u[1] = f2bf(v0[1]);
            st.u[2] = f2bf(v0[2]); st.u[3] = f2bf(v0[3]);
            st.u[4] = f2bf(v1[0]); st.u[5] = f2bf(v1[1]);
            st.u[6] = f2bf(v1[2]); st.u[7] = f2bf(v1[3]);
            *(v8s*)(lr + col) = st.v;              // 16B ds_write
        }
    }
    __syncthreads();

    // ---- super-iter: wave w covers g in [64q+8w, 64q+8w+8); free-running ----
    const int grp = lane >> 4;            // 0..3 (grp>=2 -> duplicate rows, discarded)
    const int l15 = lane & 15;
    const int rowb = (l15 & 7) * XS;      // A-operand row (b), duplicated mod 8
    const int kk0 = grp << 3;

    const float4 bias_v = *(const float4*)(bias + (l15 << 2));  // u = 4*l15 + 0..3

    const v8s* kbv = (const v8s*)kb;

    for (int q = 0; q < 4; ++q) {
        const int g0 = (q << 6) + (w << 3);   // 64q + 8w

        f32x4 acc[QG][4];
        #pragma unroll
        for (int j = 0; j < QG; ++j) {
            const int g = g0 + j;
            const int4* ip = (const int4*)(idx + (g << 5) + kk0);
            int4 ia = ip[0], ib = ip[1];
            const v8s* kg = kbv + (g << 8) + lane;
            v8s k0 = kg[0], k1 = kg[64], k2 = kg[128], k3 = kg[192];

            union { unsigned short u[8]; v8s v; } A;  // A[m=b dup][k=grp*8+jj]
            A.u[0] = lx[rowb + ia.x]; A.u[1] = lx[rowb + ia.y];
            A.u[2] = lx[rowb + ia.z]; A.u[3] = lx[rowb + ia.w];
            A.u[4] = lx[rowb + ib.x]; A.u[5] = lx[rowb + ib.y];
            A.u[6] = lx[rowb + ib.z]; A.u[7] = lx[rowb + ib.w];

            f32x4 z = {0.f, 0.f, 0.f, 0.f};
            acc[j][0] = __builtin_amdgcn_mfma_f32_16x16x32_bf16(A.v, k0, z, 0, 0, 0);
            acc[j][1] = __builtin_amdgcn_mfma_f32_16x16x32_bf16(A.v, k1, z, 0, 0, 0);
            acc[j][2] = __builtin_amdgcn_mfma_f32_16x16x32_bf16(A.v, k2, z, 0, 0, 0);
            acc[j][3] = __builtin_amdgcn_mfma_f32_16x16x32_bf16(A.v, k3, z, 0, 0, 0);
        }

        // store phase: grp<2 lanes hold real rows 0..7.
        // r-outer; per row, 8 sequential NT dwordx4 = 2KB contiguous per visit.
        if (grp < 2) {
            #pragma unroll
            for (int r = 0; r < 4; ++r) {
                float* obr = out + (size_t)(b0 + (grp << 2) + r) * (G_ * U_)
                                 + (g0 << 6) + (l15 << 2);
                #pragma unroll
                for (int j = 0; j < QG; ++j) {
                    f32x4 v;
                    v[0] = acc[j][0][r] + bias_v.x;
                    v[1] = acc[j][1][r] + bias_v.y;
                    v[2] = acc[j][2][r] + bias_v.z;
                    v[3] = acc[j][3][r] + bias_v.w;
                    v[0] = v[0] > 0.f ? v[0] : 0.f;
                    v[1] = v[1] > 0.f ? v[1] : 0.f;
                    v[2] = v[2] > 0.f ? v[2] : 0.f;
                    v[3] = v[3] > 0.f ? v[3] : 0.f;
                    __builtin_nontemporal_store(v, (f32x4*)(obr + (j << 6)));
                }
            }
        }
        // no barrier: free-running waves
    }
}

extern "C" void kernel_launch(void* const* d_in, const int* in_sizes, int n_in,
                              void* d_out, int out_size, void* d_ws, size_t ws_size,
                              hipStream_t stream) {
    const float* x    = (const float*)d_in[0];
    const float* kern = (const float*)d_in[1];
    const float* bias = (const float*)d_in[2];
    const int*   idx  = (const int*)d_in[3];
    float* out = (float*)d_out;
    unsigned short* kb = (unsigned short*)d_ws;   // 1 MiB bf16 kernel frags

    prep_kb<<<(G_ * K_ * U_ + 255) / 256, 256, 0, stream>>>(kern, kb);
    // LDS: 8*XS ushorts used (65.6KB) but allocate 100KB to force 1 block/CU
    sdense<<<B_ / ROWS, 512, 100 * 1024, stream>>>(x, kb, bias, idx, out);
}